// Round 1
// baseline (499.970 us; speedup 1.0000x reference)
//
#include <hip/hip_runtime.h>
#include <stdint.h>

// tri_att: out[n,s] = sum_d w[n,d] * x[n,d,s]
//   w[n,d] = sum_c softmax_d( bilinear )[n,c,d]
//   bilinear[n,c,d] = sum_s softmax_s(7*x)[n,c,s] * x[n,d,s]
// NB=32, C=512, S=56*56=3136. Dominant cost: 52.6 GFLOP batched GEMM -> bf16 MFMA.

#define NB 32
#define CC 512
#define SS 3136
#define SCALE 7.0f

typedef float f32x4 __attribute__((ext_vector_type(4)));
typedef __bf16 bf16x8 __attribute__((ext_vector_type(8)));

// ---------- helpers ----------
__device__ inline unsigned short f2bf(float f) {  // RNE float->bf16 bit pattern
  unsigned int u = __float_as_uint(f);
  u += 0x7fffu + ((u >> 16) & 1u);
  return (unsigned short)(u >> 16);
}

__device__ inline float wredmax(float v) {
#pragma unroll
  for (int m = 32; m >= 1; m >>= 1) v = fmaxf(v, __shfl_xor(v, m, 64));
  return v;
}
__device__ inline float wredsum(float v) {
#pragma unroll
  for (int m = 32; m >= 1; m >>= 1) v += __shfl_xor(v, m, 64);
  return v;
}

__device__ inline void load_lds16(const void* g, void* l) {
  // dest = wave-uniform base + lane*16 (lane0's pointer IS the base in our scheme)
  __builtin_amdgcn_global_load_lds(
      (const __attribute__((address_space(1))) void*)(uintptr_t)g,
      (__attribute__((address_space(3))) void*)(uintptr_t)l, 16, 0, 0);
}

// ---------- K1: softmax stats over s, emit f_norm (bf16) and f (bf16) ----------
// one block per (n,c) row; 3136 floats = 784 float4 = 3*256 + 16
__global__ __launch_bounds__(256) void k_prep(const float* __restrict__ x,
                                              unsigned short* __restrict__ a,
                                              unsigned short* __restrict__ b) {
  const int row = blockIdx.x;          // n*CC + c
  const int tid = threadIdx.x;
  const float4* xr = (const float4*)(x + (size_t)row * SS);
  float4 v0 = xr[tid];
  float4 v1 = xr[tid + 256];
  float4 v2 = xr[tid + 512];
  float4 v3 = (tid < 16) ? xr[768 + tid] : make_float4(-1e30f, -1e30f, -1e30f, -1e30f);

  float mx = fmaxf(fmaxf(fmaxf(v0.x, v0.y), fmaxf(v0.z, v0.w)),
             fmaxf(fmaxf(fmaxf(v1.x, v1.y), fmaxf(v1.z, v1.w)),
             fmaxf(fmaxf(fmaxf(v2.x, v2.y), fmaxf(v2.z, v2.w)),
                   fmaxf(fmaxf(v3.x, v3.y), fmaxf(v3.z, v3.w)))));
  __shared__ float redm[4], reds[4];
  mx = wredmax(mx);
  if ((tid & 63) == 0) redm[tid >> 6] = mx;
  __syncthreads();
  mx = fmaxf(fmaxf(redm[0], redm[1]), fmaxf(redm[2], redm[3]));

  float4 e0, e1, e2, e3;
  e0.x = __expf(SCALE * (v0.x - mx)); e0.y = __expf(SCALE * (v0.y - mx));
  e0.z = __expf(SCALE * (v0.z - mx)); e0.w = __expf(SCALE * (v0.w - mx));
  e1.x = __expf(SCALE * (v1.x - mx)); e1.y = __expf(SCALE * (v1.y - mx));
  e1.z = __expf(SCALE * (v1.z - mx)); e1.w = __expf(SCALE * (v1.w - mx));
  e2.x = __expf(SCALE * (v2.x - mx)); e2.y = __expf(SCALE * (v2.y - mx));
  e2.z = __expf(SCALE * (v2.z - mx)); e2.w = __expf(SCALE * (v2.w - mx));
  e3.x = __expf(SCALE * (v3.x - mx)); e3.y = __expf(SCALE * (v3.y - mx));
  e3.z = __expf(SCALE * (v3.z - mx)); e3.w = __expf(SCALE * (v3.w - mx));

  float s = (e0.x + e0.y + e0.z + e0.w) + (e1.x + e1.y + e1.z + e1.w) +
            (e2.x + e2.y + e2.z + e2.w) + (e3.x + e3.y + e3.z + e3.w);
  s = wredsum(s);
  if ((tid & 63) == 0) reds[tid >> 6] = s;
  __syncthreads();
  const float inv = 1.0f / (reds[0] + reds[1] + reds[2] + reds[3]);

  ushort4* ar = (ushort4*)(a + (size_t)row * SS);
  ushort4* br = (ushort4*)(b + (size_t)row * SS);
  ushort4 pa, pb;
  pa.x = f2bf(e0.x * inv); pa.y = f2bf(e0.y * inv); pa.z = f2bf(e0.z * inv); pa.w = f2bf(e0.w * inv);
  pb.x = f2bf(v0.x); pb.y = f2bf(v0.y); pb.z = f2bf(v0.z); pb.w = f2bf(v0.w);
  ar[tid] = pa; br[tid] = pb;
  pa.x = f2bf(e1.x * inv); pa.y = f2bf(e1.y * inv); pa.z = f2bf(e1.z * inv); pa.w = f2bf(e1.w * inv);
  pb.x = f2bf(v1.x); pb.y = f2bf(v1.y); pb.z = f2bf(v1.z); pb.w = f2bf(v1.w);
  ar[tid + 256] = pa; br[tid + 256] = pb;
  pa.x = f2bf(e2.x * inv); pa.y = f2bf(e2.y * inv); pa.z = f2bf(e2.z * inv); pa.w = f2bf(e2.w * inv);
  pb.x = f2bf(v2.x); pb.y = f2bf(v2.y); pb.z = f2bf(v2.z); pb.w = f2bf(v2.w);
  ar[tid + 512] = pa; br[tid + 512] = pb;
  if (tid < 16) {
    pa.x = f2bf(e3.x * inv); pa.y = f2bf(e3.y * inv); pa.z = f2bf(e3.z * inv); pa.w = f2bf(e3.w * inv);
    pb.x = f2bf(v3.x); pb.y = f2bf(v3.y); pb.z = f2bf(v3.z); pb.w = f2bf(v3.w);
    ar[768 + tid] = pa; br[768 + tid] = pb;
  }
}

// ---------- K2: batched NT GEMM, bilinear[n,c,d] = sum_s A[c,s]*B[d,s] ----------
// 128x128 tile/block (4 waves, each 64x64 = 4x4 of 16x16x32 MFMA), BK=64.
// Staging via global_load_lds width 16; XOR-swizzled LDS so ds_read_b128 is <=2-way.
#define BM 128
#define BK 64

__global__ __launch_bounds__(256) void k_gemm(const unsigned short* __restrict__ A,
                                              const unsigned short* __restrict__ B,
                                              float* __restrict__ Cmat) {
  __shared__ unsigned short sA[BM * BK];  // 16 KB
  __shared__ unsigned short sB[BM * BK];  // 16 KB
  const int n  = blockIdx.y;
  const int tm = (blockIdx.x >> 2) * BM;
  const int tn = (blockIdx.x & 3) * BM;
  const unsigned short* Ap = A + (size_t)n * CC * SS + (size_t)tm * SS;
  const unsigned short* Bp = B + (size_t)n * CC * SS + (size_t)tn * SS;
  const int tid  = threadIdx.x;
  const int lane = tid & 63;
  const int wave = tid >> 6;
  const int wm   = (wave >> 1) * 64;
  const int wn   = (wave & 1) * 64;
  const int quad = lane >> 4;
  const int rr   = lane & 15;

  f32x4 acc[4][4] = {};

  for (int k0 = 0; k0 < SS; k0 += BK) {
    // stage: chunk j (0..1023) -> LDS bytes [j*16, j*16+16): row r=j>>3,
    // stored col-group cs=j&7 holds data col-group cg = cs ^ (r&7)  (xor swizzle)
#pragma unroll
    for (int t = 0; t < 4; t++) {
      const int j  = ((t << 2) + wave) * 64 + lane;
      const int r  = j >> 3;
      const int cg = (j & 7) ^ (r & 7);
      load_lds16(Ap + (size_t)r * SS + (k0 + cg * 8), &sA[(size_t)j * 8]);
      load_lds16(Bp + (size_t)r * SS + (k0 + cg * 8), &sB[(size_t)j * 8]);
    }
    __syncthreads();  // compiler emits vmcnt(0) drain before barrier
#pragma unroll
    for (int ki = 0; ki < 2; ki++) {
      bf16x8 af[4], bfr[4];
      const int cg = ki * 4 + quad;
#pragma unroll
      for (int mt = 0; mt < 4; mt++) {
        const int r  = wm + mt * 16 + rr;
        const int cs = cg ^ (r & 7);
        af[mt] = *(const bf16x8*)&sA[(r * 8 + cs) * 8];
      }
#pragma unroll
      for (int nt = 0; nt < 4; nt++) {
        const int r  = wn + nt * 16 + rr;
        const int cs = cg ^ (r & 7);
        bfr[nt] = *(const bf16x8*)&sB[(r * 8 + cs) * 8];
      }
#pragma unroll
      for (int mt = 0; mt < 4; mt++)
#pragma unroll
        for (int nt = 0; nt < 4; nt++)
          acc[mt][nt] = __builtin_amdgcn_mfma_f32_16x16x32_bf16(af[mt], bfr[nt], acc[mt][nt], 0, 0, 0);
    }
    __syncthreads();  // all reads done before next stage overwrites LDS
  }

  // C/D layout: col = lane&15, row = quad*4 + reg
  float* Cp = Cmat + ((size_t)n << 18);
#pragma unroll
  for (int mt = 0; mt < 4; mt++) {
    const int rbase = tm + wm + mt * 16 + quad * 4;
#pragma unroll
    for (int nt = 0; nt < 4; nt++) {
      const int col = tn + wn + nt * 16 + rr;
#pragma unroll
      for (int i = 0; i < 4; i++)
        Cp[(size_t)(rbase + i) * CC + col] = acc[mt][nt][i];
    }
  }
}

// ---------- K3a: per-(n,c) softmax stats over d (512) ----------
__global__ __launch_bounds__(256) void k_rowstats(const float* __restrict__ bl,
                                                  float* __restrict__ rm,
                                                  float* __restrict__ rli) {
  const int row = blockIdx.x;
  const int tid = threadIdx.x;
  const float* r = bl + (size_t)row * CC;
  const float v0 = r[tid], v1 = r[tid + 256];
  __shared__ float redm[4], reds[4];
  float mx = wredmax(fmaxf(v0, v1));
  if ((tid & 63) == 0) redm[tid >> 6] = mx;
  __syncthreads();
  mx = fmaxf(fmaxf(redm[0], redm[1]), fmaxf(redm[2], redm[3]));
  float s = __expf(v0 - mx) + __expf(v1 - mx);
  s = wredsum(s);
  if ((tid & 63) == 0) reds[tid >> 6] = s;
  __syncthreads();
  if (tid == 0) {
    rm[row]  = mx;
    rli[row] = 1.0f / (reds[0] + reds[1] + reds[2] + reds[3]);
  }
}

// ---------- K3b: w[n,d] = sum_c exp(bl[n,c,d]-rm[n,c])*rli[n,c] ----------
__global__ __launch_bounds__(256) void k_wsum(const float* __restrict__ bl,
                                              const float* __restrict__ rm,
                                              const float* __restrict__ rli,
                                              float* __restrict__ w) {
  const int n = blockIdx.y;
  const int d = blockIdx.x * 256 + threadIdx.x;
  __shared__ float sm[CC], sl[CC];
  for (int i = threadIdx.x; i < CC; i += 256) {
    sm[i] = rm[n * CC + i];
    sl[i] = rli[n * CC + i];
  }
  __syncthreads();
  const float* p = bl + (size_t)n * CC * CC + d;
  float acc = 0.f;
#pragma unroll 4
  for (int c = 0; c < CC; c++) acc += __expf(p[(size_t)c * CC] - sm[c]) * sl[c];
  w[n * CC + d] = acc;
}

// ---------- K4: out[n,s] = sum_d w[n,d] * x[n,d,s]  (full fp32) ----------
__global__ __launch_bounds__(256) void k_out(const float* __restrict__ x,
                                             const float* __restrict__ w,
                                             float* __restrict__ out) {
  const int n = blockIdx.y;
  const int s = blockIdx.x * 256 + threadIdx.x;
  __shared__ float sw[CC];
  for (int i = threadIdx.x; i < CC; i += 256) sw[i] = w[n * CC + i];
  __syncthreads();
  if (s >= SS) return;
  const float* xp = x + (size_t)n * CC * SS + s;
  float acc = 0.f;
#pragma unroll 8
  for (int d = 0; d < CC; d++) acc += sw[d] * xp[(size_t)d * SS];
  out[n * SS + s] = acc;
}

extern "C" void kernel_launch(void* const* d_in, const int* in_sizes, int n_in,
                              void* d_out, int out_size, void* d_ws, size_t ws_size,
                              hipStream_t stream) {
  const float* x = (const float*)d_in[0];
  float* out = (float*)d_out;
  char* ws = (char*)d_ws;
  // ws layout (bytes): a_bf16 102,760,448 | b_bf16 102,760,448 | bilinear 33,554,432
  //                    | rm 65,536 | rli 65,536 | w 65,536   => total 239,271,936
  unsigned short* a_bf = (unsigned short*)ws;
  unsigned short* b_bf = (unsigned short*)(ws + 102760448ull);
  float* bl  = (float*)(ws + 205520896ull);
  float* rm  = (float*)(ws + 239075328ull);
  float* rli = (float*)(ws + 239140864ull);
  float* w   = (float*)(ws + 239206400ull);

  hipLaunchKernelGGL(k_prep,     dim3(NB * CC), dim3(256), 0, stream, x, a_bf, b_bf);
  hipLaunchKernelGGL(k_gemm,     dim3(16, NB),  dim3(256), 0, stream, a_bf, b_bf, bl);
  hipLaunchKernelGGL(k_rowstats, dim3(NB * CC), dim3(256), 0, stream, bl, rm, rli);
  hipLaunchKernelGGL(k_wsum,     dim3(2, NB),   dim3(256), 0, stream, bl, rm, rli, w);
  hipLaunchKernelGGL(k_out,      dim3(13, NB),  dim3(256), 0, stream, x, w, out);
}

// Round 2
// 445.257 us; speedup vs baseline: 1.1229x; 1.1229x over previous
//
#include <hip/hip_runtime.h>
#include <stdint.h>

// tri_att: out[n,s] = sum_d w[n,d] * x[n,d,s]
//   w[n,d] = sum_c softmax_d( bilinear )[n,c,d]
//   bilinear[n,c,d] = sum_s softmax_s(7*x)[n,c,s] * x[n,d,s]
// NB=32, C=512, S=56*56=3136. Dominant cost: 52.6 GFLOP batched GEMM -> bf16 MFMA.

#define NB 32
#define CC 512
#define SS 3136
#define SCALE 7.0f

typedef float f32x4 __attribute__((ext_vector_type(4)));
typedef __bf16 bf16x8 __attribute__((ext_vector_type(8)));

// ---------- helpers ----------
__device__ inline unsigned short f2bf(float f) {  // RNE float->bf16 bit pattern
  unsigned int u = __float_as_uint(f);
  u += 0x7fffu + ((u >> 16) & 1u);
  return (unsigned short)(u >> 16);
}

__device__ inline float wredmax(float v) {
#pragma unroll
  for (int m = 32; m >= 1; m >>= 1) v = fmaxf(v, __shfl_xor(v, m, 64));
  return v;
}
__device__ inline float wredsum(float v) {
#pragma unroll
  for (int m = 32; m >= 1; m >>= 1) v += __shfl_xor(v, m, 64);
  return v;
}

__device__ inline void load_lds16(const void* g, void* l) {
  __builtin_amdgcn_global_load_lds(
      (const __attribute__((address_space(1))) void*)(uintptr_t)g,
      (__attribute__((address_space(3))) void*)(uintptr_t)l, 16, 0, 0);
}

// ---------- K1: softmax stats over s, emit f_norm (bf16) and f (bf16) ----------
__global__ __launch_bounds__(256) void k_prep(const float* __restrict__ x,
                                              unsigned short* __restrict__ a,
                                              unsigned short* __restrict__ b) {
  const int row = blockIdx.x;          // n*CC + c
  const int tid = threadIdx.x;
  const float4* xr = (const float4*)(x + (size_t)row * SS);
  float4 v0 = xr[tid];
  float4 v1 = xr[tid + 256];
  float4 v2 = xr[tid + 512];
  float4 v3 = (tid < 16) ? xr[768 + tid] : make_float4(-1e30f, -1e30f, -1e30f, -1e30f);

  float mx = fmaxf(fmaxf(fmaxf(v0.x, v0.y), fmaxf(v0.z, v0.w)),
             fmaxf(fmaxf(fmaxf(v1.x, v1.y), fmaxf(v1.z, v1.w)),
             fmaxf(fmaxf(fmaxf(v2.x, v2.y), fmaxf(v2.z, v2.w)),
                   fmaxf(fmaxf(v3.x, v3.y), fmaxf(v3.z, v3.w)))));
  __shared__ float redm[4], reds[4];
  mx = wredmax(mx);
  if ((tid & 63) == 0) redm[tid >> 6] = mx;
  __syncthreads();
  mx = fmaxf(fmaxf(redm[0], redm[1]), fmaxf(redm[2], redm[3]));

  float4 e0, e1, e2, e3;
  e0.x = __expf(SCALE * (v0.x - mx)); e0.y = __expf(SCALE * (v0.y - mx));
  e0.z = __expf(SCALE * (v0.z - mx)); e0.w = __expf(SCALE * (v0.w - mx));
  e1.x = __expf(SCALE * (v1.x - mx)); e1.y = __expf(SCALE * (v1.y - mx));
  e1.z = __expf(SCALE * (v1.z - mx)); e1.w = __expf(SCALE * (v1.w - mx));
  e2.x = __expf(SCALE * (v2.x - mx)); e2.y = __expf(SCALE * (v2.y - mx));
  e2.z = __expf(SCALE * (v2.z - mx)); e2.w = __expf(SCALE * (v2.w - mx));
  e3.x = __expf(SCALE * (v3.x - mx)); e3.y = __expf(SCALE * (v3.y - mx));
  e3.z = __expf(SCALE * (v3.z - mx)); e3.w = __expf(SCALE * (v3.w - mx));

  float s = (e0.x + e0.y + e0.z + e0.w) + (e1.x + e1.y + e1.z + e1.w) +
            (e2.x + e2.y + e2.z + e2.w) + (e3.x + e3.y + e3.z + e3.w);
  s = wredsum(s);
  if ((tid & 63) == 0) reds[tid >> 6] = s;
  __syncthreads();
  const float inv = 1.0f / (reds[0] + reds[1] + reds[2] + reds[3]);

  ushort4* ar = (ushort4*)(a + (size_t)row * SS);
  ushort4* br = (ushort4*)(b + (size_t)row * SS);
  ushort4 pa, pb;
  pa.x = f2bf(e0.x * inv); pa.y = f2bf(e0.y * inv); pa.z = f2bf(e0.z * inv); pa.w = f2bf(e0.w * inv);
  pb.x = f2bf(v0.x); pb.y = f2bf(v0.y); pb.z = f2bf(v0.z); pb.w = f2bf(v0.w);
  ar[tid] = pa; br[tid] = pb;
  pa.x = f2bf(e1.x * inv); pa.y = f2bf(e1.y * inv); pa.z = f2bf(e1.z * inv); pa.w = f2bf(e1.w * inv);
  pb.x = f2bf(v1.x); pb.y = f2bf(v1.y); pb.z = f2bf(v1.z); pb.w = f2bf(v1.w);
  ar[tid + 256] = pa; br[tid + 256] = pb;
  pa.x = f2bf(e2.x * inv); pa.y = f2bf(e2.y * inv); pa.z = f2bf(e2.z * inv); pa.w = f2bf(e2.w * inv);
  pb.x = f2bf(v2.x); pb.y = f2bf(v2.y); pb.z = f2bf(v2.z); pb.w = f2bf(v2.w);
  ar[tid + 512] = pa; br[tid + 512] = pb;
  if (tid < 16) {
    pa.x = f2bf(e3.x * inv); pa.y = f2bf(e3.y * inv); pa.z = f2bf(e3.z * inv); pa.w = f2bf(e3.w * inv);
    pb.x = f2bf(v3.x); pb.y = f2bf(v3.y); pb.z = f2bf(v3.z); pb.w = f2bf(v3.w);
    ar[768 + tid] = pa; br[768 + tid] = pb;
  }
}

// ---------- K2: batched NT GEMM, bilinear[n,c,d] = sum_s A[c,s]*B[d,s] ----------
// 128x128 tile/block, BK=64, global_load_lds w16, XOR-swizzled LDS.
// XCD swizzle: the 4 blocks sharing an A-panel (same n,tm; tn=0..3) are mapped
// to the same XCD (assumes round-robin linear-block-id -> XCD dispatch).
#define BM 128
#define BK 64

__global__ __launch_bounds__(256) void k_gemm(const unsigned short* __restrict__ A,
                                              const unsigned short* __restrict__ B,
                                              float* __restrict__ Cmat) {
  __shared__ unsigned short sA[BM * BK];  // 16 KB
  __shared__ unsigned short sB[BM * BK];  // 16 KB
  const int lin  = blockIdx.y * gridDim.x + blockIdx.x;  // 0..511
  const int xcd  = lin & 7;
  const int slot = lin >> 3;                 // 0..63
  const int pair = xcd * 16 + (slot >> 2);   // 0..127 = (n, tm)
  const int n    = pair >> 2;
  const int tm   = (pair & 3) * BM;
  const int tn   = (slot & 3) * BM;
  const unsigned short* Ap = A + (size_t)n * CC * SS + (size_t)tm * SS;
  const unsigned short* Bp = B + (size_t)n * CC * SS + (size_t)tn * SS;
  const int tid  = threadIdx.x;
  const int lane = tid & 63;
  const int wave = tid >> 6;
  const int wm   = (wave >> 1) * 64;
  const int wn   = (wave & 1) * 64;
  const int quad = lane >> 4;
  const int rr   = lane & 15;

  f32x4 acc[4][4] = {};

  for (int k0 = 0; k0 < SS; k0 += BK) {
#pragma unroll
    for (int t = 0; t < 4; t++) {
      const int j  = ((t << 2) + wave) * 64 + lane;
      const int r  = j >> 3;
      const int cg = (j & 7) ^ (r & 7);
      load_lds16(Ap + (size_t)r * SS + (k0 + cg * 8), &sA[(size_t)j * 8]);
      load_lds16(Bp + (size_t)r * SS + (k0 + cg * 8), &sB[(size_t)j * 8]);
    }
    __syncthreads();
#pragma unroll
    for (int ki = 0; ki < 2; ki++) {
      bf16x8 af[4], bfr[4];
      const int cg = ki * 4 + quad;
#pragma unroll
      for (int mt = 0; mt < 4; mt++) {
        const int r  = wm + mt * 16 + rr;
        const int cs = cg ^ (r & 7);
        af[mt] = *(const bf16x8*)&sA[(r * 8 + cs) * 8];
      }
#pragma unroll
      for (int nt = 0; nt < 4; nt++) {
        const int r  = wn + nt * 16 + rr;
        const int cs = cg ^ (r & 7);
        bfr[nt] = *(const bf16x8*)&sB[(r * 8 + cs) * 8];
      }
#pragma unroll
      for (int mt = 0; mt < 4; mt++)
#pragma unroll
        for (int nt = 0; nt < 4; nt++)
          acc[mt][nt] = __builtin_amdgcn_mfma_f32_16x16x32_bf16(af[mt], bfr[nt], acc[mt][nt], 0, 0, 0);
    }
    __syncthreads();
  }

  float* Cp = Cmat + ((size_t)n << 18);
#pragma unroll
  for (int mt = 0; mt < 4; mt++) {
    const int rbase = tm + wm + mt * 16 + quad * 4;
#pragma unroll
    for (int nt = 0; nt < 4; nt++) {
      const int col = tn + wn + nt * 16 + rr;
#pragma unroll
      for (int i = 0; i < 4; i++)
        Cp[(size_t)(rbase + i) * CC + col] = acc[mt][nt][i];
    }
  }
}

// ---------- K3a: rinv[n,c] = 1/sum_d exp(bl[n,c,d]) ----------
// Max-free is safe: |bl| <= max|x| ~ 5.5 (bilinear is a softmax-weighted avg of f).
// One wave per row, 4 rows per block.
__global__ __launch_bounds__(256) void k_rowinv(const float* __restrict__ bl,
                                                float* __restrict__ rinv) {
  const int row  = blockIdx.x * 4 + (threadIdx.x >> 6);
  const int lane = threadIdx.x & 63;
  const float* r = bl + (size_t)row * CC;
  float s = 0.f;
#pragma unroll
  for (int j = 0; j < 8; j++) s += __expf(r[lane + j * 64]);
  s = wredsum(s);
  if (lane == 0) rinv[row] = 1.0f / s;
}

// ---------- K3b: wp[n,h,d] = sum_{c in half h} exp(bl[n,c,d])*rinv[n,c] ----------
__global__ __launch_bounds__(256) void k_wsum(const float* __restrict__ bl,
                                              const float* __restrict__ rinv,
                                              float* __restrict__ wp) {
  const int n = blockIdx.y;
  const int h = blockIdx.x & 1;          // c half
  const int d = (blockIdx.x >> 1) * 256 + threadIdx.x;
  __shared__ float sinv[256];
  sinv[threadIdx.x] = rinv[n * CC + h * 256 + threadIdx.x];
  __syncthreads();
  const float* p = bl + (size_t)n * CC * CC + (size_t)(h * 256) * CC + d;
  float acc = 0.f;
#pragma unroll 8
  for (int c = 0; c < 256; c++) acc += __expf(p[(size_t)c * CC]) * sinv[c];
  wp[((size_t)n * 2 + h) * CC + d] = acc;
}

// ---------- K4: out[n,s] = sum_d w[n,d] * bf16(x)[n,d,s] ----------
__global__ __launch_bounds__(256) void k_out(const unsigned short* __restrict__ b,
                                             const float* __restrict__ wp,
                                             float* __restrict__ out) {
  const int n = blockIdx.y;
  const int s0 = (blockIdx.x * 256 + threadIdx.x) * 2;
  __shared__ float sw[CC];
  for (int i = threadIdx.x; i < CC; i += 256)
    sw[i] = wp[(size_t)n * 2 * CC + i] + wp[((size_t)n * 2 + 1) * CC + i];
  __syncthreads();
  if (s0 >= SS) return;
  const unsigned short* bp = b + (size_t)n * CC * SS + s0;
  float a0 = 0.f, a1 = 0.f;
#pragma unroll 8
  for (int d = 0; d < CC; d++) {
    const uint32_t u = *(const uint32_t*)(bp + (size_t)d * SS);
    a0 += sw[d] * __uint_as_float(u << 16);
    a1 += sw[d] * __uint_as_float(u & 0xffff0000u);
  }
  *(float2*)(out + (size_t)n * SS + s0) = make_float2(a0, a1);
}

extern "C" void kernel_launch(void* const* d_in, const int* in_sizes, int n_in,
                              void* d_out, int out_size, void* d_ws, size_t ws_size,
                              hipStream_t stream) {
  const float* x = (const float*)d_in[0];
  float* out = (float*)d_out;
  char* ws = (char*)d_ws;
  // ws layout: a_bf 102,760,448 | b_bf 102,760,448 | bl 33,554,432 | rinv 65,536 | wp 131,072
  unsigned short* a_bf = (unsigned short*)ws;
  unsigned short* b_bf = (unsigned short*)(ws + 102760448ull);
  float* bl   = (float*)(ws + 205520896ull);
  float* rinv = (float*)(ws + 239075328ull);
  float* wp   = (float*)(ws + 239140864ull);

  hipLaunchKernelGGL(k_prep,   dim3(NB * CC),     dim3(256), 0, stream, x, a_bf, b_bf);
  hipLaunchKernelGGL(k_gemm,   dim3(16, NB),      dim3(256), 0, stream, a_bf, b_bf, bl);
  hipLaunchKernelGGL(k_rowinv, dim3(NB * CC / 4), dim3(256), 0, stream, bl, rinv);
  hipLaunchKernelGGL(k_wsum,   dim3(4, NB),       dim3(256), 0, stream, bl, rinv, wp);
  hipLaunchKernelGGL(k_out,    dim3(7, NB),       dim3(256), 0, stream, b_bf, wp, out);
}

// Round 3
// 423.006 us; speedup vs baseline: 1.1819x; 1.0526x over previous
//
#include <hip/hip_runtime.h>
#include <stdint.h>

// tri_att: out[n,s] = sum_d w[n,d] * x[n,d,s]
//   w[n,d] = sum_c softmax_d( bilinear )[n,c,d]
//   bilinear[n,c,d] = sum_s softmax_s(7*x)[n,c,s] * x[n,d,s]
// NB=32, C=512, S=56*56=3136. Dominant cost: 52.6 GFLOP batched GEMM -> bf16 MFMA.
// R3: row-exp-sum fused into gemm epilogue (atomics, XCD-local); k_wsum/k_out
// re-parallelized (512/896 blocks) with partial slices + atomicAdd into zeroed out.

#define NB 32
#define CC 512
#define SS 3136
#define SCALE 7.0f

typedef float f32x4 __attribute__((ext_vector_type(4)));
typedef __bf16 bf16x8 __attribute__((ext_vector_type(8)));

// ---------- helpers ----------
__device__ inline unsigned short f2bf(float f) {  // RNE float->bf16 bit pattern
  unsigned int u = __float_as_uint(f);
  u += 0x7fffu + ((u >> 16) & 1u);
  return (unsigned short)(u >> 16);
}

__device__ inline float wredmax(float v) {
#pragma unroll
  for (int m = 32; m >= 1; m >>= 1) v = fmaxf(v, __shfl_xor(v, m, 64));
  return v;
}
__device__ inline float wredsum(float v) {
#pragma unroll
  for (int m = 32; m >= 1; m >>= 1) v += __shfl_xor(v, m, 64);
  return v;
}

__device__ inline void load_lds16(const void* g, void* l) {
  __builtin_amdgcn_global_load_lds(
      (const __attribute__((address_space(1))) void*)(uintptr_t)g,
      (__attribute__((address_space(3))) void*)(uintptr_t)l, 16, 0, 0);
}

// ---------- K1: softmax over s -> a=f_norm (bf16), b=f (bf16); zero esum ----------
__global__ __launch_bounds__(256) void k_prep(const float* __restrict__ x,
                                              unsigned short* __restrict__ a,
                                              unsigned short* __restrict__ b,
                                              float* __restrict__ esum) {
  const int row = blockIdx.x;          // n*CC + c
  const int tid = threadIdx.x;
  if (tid == 0) esum[row] = 0.f;       // consumed by k_gemm (next kernel)
  const float4* xr = (const float4*)(x + (size_t)row * SS);
  float4 v0 = xr[tid];
  float4 v1 = xr[tid + 256];
  float4 v2 = xr[tid + 512];
  float4 v3 = (tid < 16) ? xr[768 + tid] : make_float4(-1e30f, -1e30f, -1e30f, -1e30f);

  float mx = fmaxf(fmaxf(fmaxf(v0.x, v0.y), fmaxf(v0.z, v0.w)),
             fmaxf(fmaxf(fmaxf(v1.x, v1.y), fmaxf(v1.z, v1.w)),
             fmaxf(fmaxf(fmaxf(v2.x, v2.y), fmaxf(v2.z, v2.w)),
                   fmaxf(fmaxf(v3.x, v3.y), fmaxf(v3.z, v3.w)))));
  __shared__ float redm[4], reds[4];
  mx = wredmax(mx);
  if ((tid & 63) == 0) redm[tid >> 6] = mx;
  __syncthreads();
  mx = fmaxf(fmaxf(redm[0], redm[1]), fmaxf(redm[2], redm[3]));

  float4 e0, e1, e2, e3;
  e0.x = __expf(SCALE * (v0.x - mx)); e0.y = __expf(SCALE * (v0.y - mx));
  e0.z = __expf(SCALE * (v0.z - mx)); e0.w = __expf(SCALE * (v0.w - mx));
  e1.x = __expf(SCALE * (v1.x - mx)); e1.y = __expf(SCALE * (v1.y - mx));
  e1.z = __expf(SCALE * (v1.z - mx)); e1.w = __expf(SCALE * (v1.w - mx));
  e2.x = __expf(SCALE * (v2.x - mx)); e2.y = __expf(SCALE * (v2.y - mx));
  e2.z = __expf(SCALE * (v2.z - mx)); e2.w = __expf(SCALE * (v2.w - mx));
  e3.x = __expf(SCALE * (v3.x - mx)); e3.y = __expf(SCALE * (v3.y - mx));
  e3.z = __expf(SCALE * (v3.z - mx)); e3.w = __expf(SCALE * (v3.w - mx));

  float s = (e0.x + e0.y + e0.z + e0.w) + (e1.x + e1.y + e1.z + e1.w) +
            (e2.x + e2.y + e2.z + e2.w) + (e3.x + e3.y + e3.z + e3.w);
  s = wredsum(s);
  if ((tid & 63) == 0) reds[tid >> 6] = s;
  __syncthreads();
  const float inv = 1.0f / (reds[0] + reds[1] + reds[2] + reds[3]);

  ushort4* ar = (ushort4*)(a + (size_t)row * SS);
  ushort4* br = (ushort4*)(b + (size_t)row * SS);
  ushort4 pa, pb;
  pa.x = f2bf(e0.x * inv); pa.y = f2bf(e0.y * inv); pa.z = f2bf(e0.z * inv); pa.w = f2bf(e0.w * inv);
  pb.x = f2bf(v0.x); pb.y = f2bf(v0.y); pb.z = f2bf(v0.z); pb.w = f2bf(v0.w);
  ar[tid] = pa; br[tid] = pb;
  pa.x = f2bf(e1.x * inv); pa.y = f2bf(e1.y * inv); pa.z = f2bf(e1.z * inv); pa.w = f2bf(e1.w * inv);
  pb.x = f2bf(v1.x); pb.y = f2bf(v1.y); pb.z = f2bf(v1.z); pb.w = f2bf(v1.w);
  ar[tid + 256] = pa; br[tid + 256] = pb;
  pa.x = f2bf(e2.x * inv); pa.y = f2bf(e2.y * inv); pa.z = f2bf(e2.z * inv); pa.w = f2bf(e2.w * inv);
  pb.x = f2bf(v2.x); pb.y = f2bf(v2.y); pb.z = f2bf(v2.z); pb.w = f2bf(v2.w);
  ar[tid + 512] = pa; br[tid + 512] = pb;
  if (tid < 16) {
    pa.x = f2bf(e3.x * inv); pa.y = f2bf(e3.y * inv); pa.z = f2bf(e3.z * inv); pa.w = f2bf(e3.w * inv);
    pb.x = f2bf(v3.x); pb.y = f2bf(v3.y); pb.z = f2bf(v3.z); pb.w = f2bf(v3.w);
    ar[768 + tid] = pa; br[768 + tid] = pb;
  }
}

// ---------- K2: batched NT GEMM + fused row exp-sum ----------
// 128x128 tile/block, BK=64, global_load_lds w16, XOR-swizzled LDS.
// XCD swizzle: each n's 16 blocks land on one XCD -> A/B panel L2 reuse AND
// esum atomics stay XCD-local.
#define BM 128
#define BK 64

__global__ __launch_bounds__(256) void k_gemm(const unsigned short* __restrict__ A,
                                              const unsigned short* __restrict__ B,
                                              float* __restrict__ Cmat,
                                              float* __restrict__ esum) {
  __shared__ unsigned short sA[BM * BK];  // 16 KB
  __shared__ unsigned short sB[BM * BK];  // 16 KB
  const int lin  = blockIdx.y * gridDim.x + blockIdx.x;  // 0..511
  const int xcd  = lin & 7;
  const int slot = lin >> 3;                 // 0..63
  const int pair = xcd * 16 + (slot >> 2);   // 0..127 = (n, tm)
  const int n    = pair >> 2;
  const int tm   = (pair & 3) * BM;
  const int tn   = (slot & 3) * BM;
  const unsigned short* Ap = A + (size_t)n * CC * SS + (size_t)tm * SS;
  const unsigned short* Bp = B + (size_t)n * CC * SS + (size_t)tn * SS;
  const int tid  = threadIdx.x;
  const int lane = tid & 63;
  const int wave = tid >> 6;
  const int wm   = (wave >> 1) * 64;
  const int wn   = (wave & 1) * 64;
  const int quad = lane >> 4;
  const int rr   = lane & 15;

  f32x4 acc[4][4] = {};

  for (int k0 = 0; k0 < SS; k0 += BK) {
#pragma unroll
    for (int t = 0; t < 4; t++) {
      const int j  = ((t << 2) + wave) * 64 + lane;
      const int r  = j >> 3;
      const int cg = (j & 7) ^ (r & 7);
      load_lds16(Ap + (size_t)r * SS + (k0 + cg * 8), &sA[(size_t)j * 8]);
      load_lds16(Bp + (size_t)r * SS + (k0 + cg * 8), &sB[(size_t)j * 8]);
    }
    __syncthreads();
#pragma unroll
    for (int ki = 0; ki < 2; ki++) {
      bf16x8 af[4], bfr[4];
      const int cg = ki * 4 + quad;
#pragma unroll
      for (int mt = 0; mt < 4; mt++) {
        const int r  = wm + mt * 16 + rr;
        const int cs = cg ^ (r & 7);
        af[mt] = *(const bf16x8*)&sA[(r * 8 + cs) * 8];
      }
#pragma unroll
      for (int nt = 0; nt < 4; nt++) {
        const int r  = wn + nt * 16 + rr;
        const int cs = cg ^ (r & 7);
        bfr[nt] = *(const bf16x8*)&sB[(r * 8 + cs) * 8];
      }
#pragma unroll
      for (int mt = 0; mt < 4; mt++)
#pragma unroll
        for (int nt = 0; nt < 4; nt++)
          acc[mt][nt] = __builtin_amdgcn_mfma_f32_16x16x32_bf16(af[mt], bfr[nt], acc[mt][nt], 0, 0, 0);
    }
    __syncthreads();
  }

  // C/D layout: col = lane&15, row = quad*4 + reg
  float* Cp = Cmat + ((size_t)n << 18);
#pragma unroll
  for (int mt = 0; mt < 4; mt++) {
    const int rbase = tm + wm + mt * 16 + quad * 4;
#pragma unroll
    for (int nt = 0; nt < 4; nt++) {
      const int col = tn + wn + nt * 16 + rr;
#pragma unroll
      for (int i = 0; i < 4; i++)
        Cp[(size_t)(rbase + i) * CC + col] = acc[mt][nt][i];
    }
  }

  // fused: esum[n,row] += sum over this block's 128 cols of exp(bilinear)
  // (max-free exp is safe: |bl| <= max|f| ~ 5.5)
#pragma unroll
  for (int mt = 0; mt < 4; mt++) {
#pragma unroll
    for (int i = 0; i < 4; i++) {
      float v = __expf(acc[mt][0][i]) + __expf(acc[mt][1][i]) +
                __expf(acc[mt][2][i]) + __expf(acc[mt][3][i]);
#pragma unroll
      for (int m = 8; m >= 1; m >>= 1) v += __shfl_xor(v, m, 64);  // reduce rr within quad
      if (rr == 0)
        atomicAdd(&esum[n * CC + tm + wm + mt * 16 + quad * 4 + i], v);
    }
  }
}

// ---------- K3: wp[n,g,d] = sum_{c in group g} exp(bl[n,c,d]) / esum[n,c]; zero out ----------
// grid (16, NB): x = dchunk*8 + cgroup; 512 blocks.
__global__ __launch_bounds__(256) void k_wsum(const float* __restrict__ bl,
                                              const float* __restrict__ esum,
                                              float* __restrict__ wp,
                                              float* __restrict__ outz) {
  const int n  = blockIdx.y;
  const int g  = blockIdx.x & 7;        // c-group of 64
  const int d  = (blockIdx.x >> 3) * 256 + threadIdx.x;
  __shared__ float sinv[64];
  if (threadIdx.x < 64) sinv[threadIdx.x] = 1.0f / esum[n * CC + g * 64 + threadIdx.x];
  __syncthreads();
  const float* p = bl + (size_t)n * CC * CC + (size_t)(g * 64) * CC + d;
  float acc = 0.f;
#pragma unroll 8
  for (int c = 0; c < 64; c++) acc += __expf(p[(size_t)c * CC]) * sinv[c];
  wp[((size_t)n * 8 + g) * CC + d] = acc;
  // zero out[] for k_out's atomics (512*256 = 131072 >= NB*SS = 100352)
  const int idx = (blockIdx.y * 16 + blockIdx.x) * 256 + threadIdx.x;
  if (idx < NB * SS) outz[idx] = 0.f;
}

// ---------- K4: out[n,s] += sum_{d in quarter} w[n,d] * bf16(x)[n,d,s] ----------
// grid (7, NB*4): y = n*4 + dquarter; 896 blocks; atomicAdd into zeroed out.
__global__ __launch_bounds__(256) void k_out(const unsigned short* __restrict__ b,
                                             const float* __restrict__ wp,
                                             float* __restrict__ out) {
  const int n  = blockIdx.y >> 2;
  const int dq = blockIdx.y & 3;        // d-quarter of 128
  const int s0 = (blockIdx.x * 256 + threadIdx.x) * 2;
  __shared__ float sw[128];
  if (threadIdx.x < 128) {
    float v = 0.f;
#pragma unroll
    for (int g = 0; g < 8; g++) v += wp[((size_t)n * 8 + g) * CC + dq * 128 + threadIdx.x];
    sw[threadIdx.x] = v;
  }
  __syncthreads();
  if (s0 >= SS) return;
  const unsigned short* bp = b + (size_t)n * CC * SS + (size_t)(dq * 128) * SS + s0;
  float a0 = 0.f, a1 = 0.f;
#pragma unroll 8
  for (int d = 0; d < 128; d++) {
    const uint32_t u = *(const uint32_t*)(bp + (size_t)d * SS);
    a0 += sw[d] * __uint_as_float(u << 16);
    a1 += sw[d] * __uint_as_float(u & 0xffff0000u);
  }
  atomicAdd(&out[(size_t)n * SS + s0], a0);
  atomicAdd(&out[(size_t)n * SS + s0 + 1], a1);
}

extern "C" void kernel_launch(void* const* d_in, const int* in_sizes, int n_in,
                              void* d_out, int out_size, void* d_ws, size_t ws_size,
                              hipStream_t stream) {
  const float* x = (const float*)d_in[0];
  float* out = (float*)d_out;
  char* ws = (char*)d_ws;
  // ws layout: a_bf 102,760,448 | b_bf 102,760,448 | bl 33,554,432 | esum 65,536 | wp 524,288
  unsigned short* a_bf = (unsigned short*)ws;
  unsigned short* b_bf = (unsigned short*)(ws + 102760448ull);
  float* bl   = (float*)(ws + 205520896ull);
  float* esum = (float*)(ws + 239075328ull);
  float* wp   = (float*)(ws + 239140864ull);

  hipLaunchKernelGGL(k_prep, dim3(NB * CC), dim3(256), 0, stream, x, a_bf, b_bf, esum);
  hipLaunchKernelGGL(k_gemm, dim3(16, NB),  dim3(256), 0, stream, a_bf, b_bf, bl, esum);
  hipLaunchKernelGGL(k_wsum, dim3(16, NB),  dim3(256), 0, stream, bl, esum, wp, out);
  hipLaunchKernelGGL(k_out,  dim3(7, NB * 4), dim3(256), 0, stream, b_bf, wp, out);
}

// Round 4
// 418.088 us; speedup vs baseline: 1.1958x; 1.0118x over previous
//
#include <hip/hip_runtime.h>
#include <stdint.h>

// tri_att: out[n,s] = sum_d w[n,d] * x[n,d,s]
//   w[n,d] = sum_c softmax_d( bilinear )[n,c,d]
//   bilinear[n,c,d] = sum_s softmax_s(7*x)[n,c,s] * x[n,d,s]
// NB=32, C=512, S=56*56=3136. Dominant cost: 52.6 GFLOP batched GEMM -> bf16 MFMA.
// R4: gemm epilogue stores p=exp(bilinear) as bf16 (16.8 MB) instead of fp32 bl;
// k_wsum becomes pure FMA over bf16 p, XCD-aligned with gemm's n->XCD mapping.

#define NB 32
#define CC 512
#define SS 3136
#define SCALE 7.0f

typedef float f32x4 __attribute__((ext_vector_type(4)));
typedef __bf16 bf16x8 __attribute__((ext_vector_type(8)));

// ---------- helpers ----------
__device__ inline unsigned short f2bf(float f) {  // RNE float->bf16 bit pattern
  unsigned int u = __float_as_uint(f);
  u += 0x7fffu + ((u >> 16) & 1u);
  return (unsigned short)(u >> 16);
}
__device__ inline float bf2f(unsigned short u) {
  return __uint_as_float((uint32_t)u << 16);
}

__device__ inline float wredmax(float v) {
#pragma unroll
  for (int m = 32; m >= 1; m >>= 1) v = fmaxf(v, __shfl_xor(v, m, 64));
  return v;
}
__device__ inline float wredsum(float v) {
#pragma unroll
  for (int m = 32; m >= 1; m >>= 1) v += __shfl_xor(v, m, 64);
  return v;
}

__device__ inline void load_lds16(const void* g, void* l) {
  __builtin_amdgcn_global_load_lds(
      (const __attribute__((address_space(1))) void*)(uintptr_t)g,
      (__attribute__((address_space(3))) void*)(uintptr_t)l, 16, 0, 0);
}

// ---------- K1: softmax over s -> a=f_norm (bf16), b=f (bf16); zero esum ----------
__global__ __launch_bounds__(256) void k_prep(const float* __restrict__ x,
                                              unsigned short* __restrict__ a,
                                              unsigned short* __restrict__ b,
                                              float* __restrict__ esum) {
  const int row = blockIdx.x;          // n*CC + c
  const int tid = threadIdx.x;
  if (tid == 0) esum[row] = 0.f;       // consumed by k_gemm (next kernel)
  const float4* xr = (const float4*)(x + (size_t)row * SS);
  float4 v0 = xr[tid];
  float4 v1 = xr[tid + 256];
  float4 v2 = xr[tid + 512];
  float4 v3 = (tid < 16) ? xr[768 + tid] : make_float4(-1e30f, -1e30f, -1e30f, -1e30f);

  float mx = fmaxf(fmaxf(fmaxf(v0.x, v0.y), fmaxf(v0.z, v0.w)),
             fmaxf(fmaxf(fmaxf(v1.x, v1.y), fmaxf(v1.z, v1.w)),
             fmaxf(fmaxf(fmaxf(v2.x, v2.y), fmaxf(v2.z, v2.w)),
                   fmaxf(fmaxf(v3.x, v3.y), fmaxf(v3.z, v3.w)))));
  __shared__ float redm[4], reds[4];
  mx = wredmax(mx);
  if ((tid & 63) == 0) redm[tid >> 6] = mx;
  __syncthreads();
  mx = fmaxf(fmaxf(redm[0], redm[1]), fmaxf(redm[2], redm[3]));

  float4 e0, e1, e2, e3;
  e0.x = __expf(SCALE * (v0.x - mx)); e0.y = __expf(SCALE * (v0.y - mx));
  e0.z = __expf(SCALE * (v0.z - mx)); e0.w = __expf(SCALE * (v0.w - mx));
  e1.x = __expf(SCALE * (v1.x - mx)); e1.y = __expf(SCALE * (v1.y - mx));
  e1.z = __expf(SCALE * (v1.z - mx)); e1.w = __expf(SCALE * (v1.w - mx));
  e2.x = __expf(SCALE * (v2.x - mx)); e2.y = __expf(SCALE * (v2.y - mx));
  e2.z = __expf(SCALE * (v2.z - mx)); e2.w = __expf(SCALE * (v2.w - mx));
  e3.x = __expf(SCALE * (v3.x - mx)); e3.y = __expf(SCALE * (v3.y - mx));
  e3.z = __expf(SCALE * (v3.z - mx)); e3.w = __expf(SCALE * (v3.w - mx));

  float s = (e0.x + e0.y + e0.z + e0.w) + (e1.x + e1.y + e1.z + e1.w) +
            (e2.x + e2.y + e2.z + e2.w) + (e3.x + e3.y + e3.z + e3.w);
  s = wredsum(s);
  if ((tid & 63) == 0) reds[tid >> 6] = s;
  __syncthreads();
  const float inv = 1.0f / (reds[0] + reds[1] + reds[2] + reds[3]);

  ushort4* ar = (ushort4*)(a + (size_t)row * SS);
  ushort4* br = (ushort4*)(b + (size_t)row * SS);
  ushort4 pa, pb;
  pa.x = f2bf(e0.x * inv); pa.y = f2bf(e0.y * inv); pa.z = f2bf(e0.z * inv); pa.w = f2bf(e0.w * inv);
  pb.x = f2bf(v0.x); pb.y = f2bf(v0.y); pb.z = f2bf(v0.z); pb.w = f2bf(v0.w);
  ar[tid] = pa; br[tid] = pb;
  pa.x = f2bf(e1.x * inv); pa.y = f2bf(e1.y * inv); pa.z = f2bf(e1.z * inv); pa.w = f2bf(e1.w * inv);
  pb.x = f2bf(v1.x); pb.y = f2bf(v1.y); pb.z = f2bf(v1.z); pb.w = f2bf(v1.w);
  ar[tid + 256] = pa; br[tid + 256] = pb;
  pa.x = f2bf(e2.x * inv); pa.y = f2bf(e2.y * inv); pa.z = f2bf(e2.z * inv); pa.w = f2bf(e2.w * inv);
  pb.x = f2bf(v2.x); pb.y = f2bf(v2.y); pb.z = f2bf(v2.z); pb.w = f2bf(v2.w);
  ar[tid + 512] = pa; br[tid + 512] = pb;
  if (tid < 16) {
    pa.x = f2bf(e3.x * inv); pa.y = f2bf(e3.y * inv); pa.z = f2bf(e3.z * inv); pa.w = f2bf(e3.w * inv);
    pb.x = f2bf(v3.x); pb.y = f2bf(v3.y); pb.z = f2bf(v3.z); pb.w = f2bf(v3.w);
    ar[768 + tid] = pa; br[768 + tid] = pb;
  }
}

// ---------- K2: batched NT GEMM -> p = exp(bilinear) (bf16) + fused row exp-sum ----------
// 128x128 tile/block, BK=64, global_load_lds w16, XOR-swizzled LDS.
// XCD swizzle: XCD x owns n in {4x..4x+3} -> A/B panel L2 reuse, XCD-local atomics.
#define BM 128
#define BK 64

__global__ __launch_bounds__(256) void k_gemm(const unsigned short* __restrict__ A,
                                              const unsigned short* __restrict__ B,
                                              unsigned short* __restrict__ P,
                                              float* __restrict__ esum) {
  __shared__ unsigned short sA[BM * BK];  // 16 KB
  __shared__ unsigned short sB[BM * BK];  // 16 KB
  const int lin  = blockIdx.y * gridDim.x + blockIdx.x;  // 0..511
  const int xcd  = lin & 7;
  const int slot = lin >> 3;                 // 0..63
  const int pair = xcd * 16 + (slot >> 2);   // 0..127
  const int n    = pair >> 2;                // = xcd*4 + (slot>>4)
  const int tm   = (pair & 3) * BM;
  const int tn   = (slot & 3) * BM;
  const unsigned short* Ap = A + (size_t)n * CC * SS + (size_t)tm * SS;
  const unsigned short* Bp = B + (size_t)n * CC * SS + (size_t)tn * SS;
  const int tid  = threadIdx.x;
  const int lane = tid & 63;
  const int wave = tid >> 6;
  const int wm   = (wave >> 1) * 64;
  const int wn   = (wave & 1) * 64;
  const int quad = lane >> 4;
  const int rr   = lane & 15;

  f32x4 acc[4][4] = {};

  for (int k0 = 0; k0 < SS; k0 += BK) {
#pragma unroll
    for (int t = 0; t < 4; t++) {
      const int j  = ((t << 2) + wave) * 64 + lane;
      const int r  = j >> 3;
      const int cg = (j & 7) ^ (r & 7);
      load_lds16(Ap + (size_t)r * SS + (k0 + cg * 8), &sA[(size_t)j * 8]);
      load_lds16(Bp + (size_t)r * SS + (k0 + cg * 8), &sB[(size_t)j * 8]);
    }
    __syncthreads();
#pragma unroll
    for (int ki = 0; ki < 2; ki++) {
      bf16x8 af[4], bfr[4];
      const int cg = ki * 4 + quad;
#pragma unroll
      for (int mt = 0; mt < 4; mt++) {
        const int r  = wm + mt * 16 + rr;
        const int cs = cg ^ (r & 7);
        af[mt] = *(const bf16x8*)&sA[(r * 8 + cs) * 8];
      }
#pragma unroll
      for (int nt = 0; nt < 4; nt++) {
        const int r  = wn + nt * 16 + rr;
        const int cs = cg ^ (r & 7);
        bfr[nt] = *(const bf16x8*)&sB[(r * 8 + cs) * 8];
      }
#pragma unroll
      for (int mt = 0; mt < 4; mt++)
#pragma unroll
        for (int nt = 0; nt < 4; nt++)
          acc[mt][nt] = __builtin_amdgcn_mfma_f32_16x16x32_bf16(af[mt], bfr[nt], acc[mt][nt], 0, 0, 0);
    }
    __syncthreads();
  }

  // Epilogue: p = exp(bilinear) stored bf16 (max-free safe: |bl| <= ~5.5);
  // esum[n,row] += row-sums via quad shuffle-reduce + XCD-local atomics.
  // C/D layout: col = lane&15, row = quad*4 + reg.
  unsigned short* Pp = P + ((size_t)n << 18);
#pragma unroll
  for (int mt = 0; mt < 4; mt++) {
    const int rbase = tm + wm + mt * 16 + quad * 4;
    float rs[4] = {0.f, 0.f, 0.f, 0.f};
#pragma unroll
    for (int nt = 0; nt < 4; nt++) {
      const int col = tn + wn + nt * 16 + rr;
#pragma unroll
      for (int i = 0; i < 4; i++) {
        const float e = __expf(acc[mt][nt][i]);
        rs[i] += e;
        Pp[(size_t)(rbase + i) * CC + col] = f2bf(e);
      }
    }
#pragma unroll
    for (int i = 0; i < 4; i++) {
      float v = rs[i];
#pragma unroll
      for (int m = 8; m >= 1; m >>= 1) v += __shfl_xor(v, m, 64);  // reduce rr
      if (rr == 0) atomicAdd(&esum[n * CC + rbase + i], v);
    }
  }
}

// ---------- K3: wp[n,g,d] = sum_{c in group g} p[n,c,d] / esum[n,c]; zero out ----------
// 512 blocks, XCD-aligned with gemm's n->XCD mapping (p reads hit local L2).
__global__ __launch_bounds__(256) void k_wsum(const unsigned short* __restrict__ P,
                                              const float* __restrict__ esum,
                                              float* __restrict__ wp,
                                              float* __restrict__ outz) {
  const int lin  = blockIdx.y * gridDim.x + blockIdx.x;  // 0..511
  const int xcd  = lin & 7;
  const int slot = lin >> 3;           // 0..63
  const int n    = xcd * 4 + (slot & 3);
  const int g    = (slot >> 2) & 7;    // c-group of 64
  const int d    = (slot >> 5) * 256 + threadIdx.x;
  __shared__ float sinv[64];
  if (threadIdx.x < 64) sinv[threadIdx.x] = 1.0f / esum[n * CC + g * 64 + threadIdx.x];
  __syncthreads();
  const unsigned short* p = P + (size_t)n * CC * CC + (size_t)(g * 64) * CC + d;
  float acc = 0.f;
#pragma unroll 8
  for (int c = 0; c < 64; c++) acc += bf2f(p[(size_t)c * CC]) * sinv[c];
  wp[((size_t)n * 8 + g) * CC + d] = acc;
  // zero out[] for k_out's atomics (512*256 = 131072 >= NB*SS = 100352)
  const int idx = lin * 256 + threadIdx.x;
  if (idx < NB * SS) outz[idx] = 0.f;
}

// ---------- K4: out[n,s] += sum_{d in quarter} w[n,d] * bf16(x)[n,d,s] ----------
__global__ __launch_bounds__(256) void k_out(const unsigned short* __restrict__ b,
                                             const float* __restrict__ wp,
                                             float* __restrict__ out) {
  const int n  = blockIdx.y >> 2;
  const int dq = blockIdx.y & 3;        // d-quarter of 128
  const int s0 = (blockIdx.x * 256 + threadIdx.x) * 2;
  __shared__ float sw[128];
  if (threadIdx.x < 128) {
    float v = 0.f;
#pragma unroll
    for (int g = 0; g < 8; g++) v += wp[((size_t)n * 8 + g) * CC + dq * 128 + threadIdx.x];
    sw[threadIdx.x] = v;
  }
  __syncthreads();
  if (s0 >= SS) return;
  const unsigned short* bp = b + (size_t)n * CC * SS + (size_t)(dq * 128) * SS + s0;
  float a0 = 0.f, a1 = 0.f;
#pragma unroll 8
  for (int d = 0; d < 128; d++) {
    const uint32_t u = *(const uint32_t*)(bp + (size_t)d * SS);
    a0 += sw[d] * __uint_as_float(u << 16);
    a1 += sw[d] * __uint_as_float(u & 0xffff0000u);
  }
  atomicAdd(&out[(size_t)n * SS + s0], a0);
  atomicAdd(&out[(size_t)n * SS + s0 + 1], a1);
}

extern "C" void kernel_launch(void* const* d_in, const int* in_sizes, int n_in,
                              void* d_out, int out_size, void* d_ws, size_t ws_size,
                              hipStream_t stream) {
  const float* x = (const float*)d_in[0];
  float* out = (float*)d_out;
  char* ws = (char*)d_ws;
  // ws: a_bf 102,760,448 | b_bf 102,760,448 | p(bf16) 16,777,216 | esum 65,536 | wp 524,288
  unsigned short* a_bf = (unsigned short*)ws;
  unsigned short* b_bf = (unsigned short*)(ws + 102760448ull);
  unsigned short* pmat = (unsigned short*)(ws + 205520896ull);
  float* esum = (float*)(ws + 222298112ull);
  float* wp   = (float*)(ws + 222363648ull);

  hipLaunchKernelGGL(k_prep, dim3(NB * CC),   dim3(256), 0, stream, x, a_bf, b_bf, esum);
  hipLaunchKernelGGL(k_gemm, dim3(16, NB),    dim3(256), 0, stream, a_bf, b_bf, pmat, esum);
  hipLaunchKernelGGL(k_wsum, dim3(16, NB),    dim3(256), 0, stream, pmat, esum, wp, out);
  hipLaunchKernelGGL(k_out,  dim3(7, NB * 4), dim3(256), 0, stream, b_bf, wp, out);
}